// Round 16
// baseline (463.194 us; speedup 1.0000x reference)
//
#include <hip/hip_runtime.h>
#include <math.h>

// CepstrumToImpulseResponse: per row r (131072 rows):
//   h[0] = exp(c[0]);  h[n] = (1/n) * sum_{k=1}^{min(n,255)} (k*c_k) * h[n-k]
//
// R16 = R15 + three arithmetic-preserving addressing/control trims:
//  (m1) RING MIRROR: bytes [0,48) of the 512B ring are mirrored at
//       [512,560). Window chunk reads become base + {0,16,32,48} with NO
//       per-chunk wrap -> one rolling offset (2 VALU/iter vs 8) and the
//       +16/+32/+48 fold into ds_read offset immediates. Mirror upkeep:
//       one extra (wave-uniform predicated) ds_write when wo < 48.
//  (m2) Phase-2 full 8x unroll (6 blocks x 8 bodies, ping-pong kept):
//       staging compare has literal u; flush branch is compile-time (u==7).
//  (m3) Phase-1 b1 = b0+16 without the &508 (mirror covers it).
// All three are bit-identical transforms -- absmax must stay 2.441406e-4.
//
// Carried: three-phase window (64/128/256 for it<8/<16/>=16), per-row f16
// ring, fdot2 MACs (1 MAC/lane/cyc = HW max, proven across pk_f32/fdot2/
// pk_fma_f16), DPP-fused butterfly reduce, f32 serial fixup k=1..7, lane-7
// register forwarding, 1-iter prefetch, register output staging, 256B/row
// coalesced flush. Launch bounds (256,4) pinned: (256,8) spilled twice.

constexpr int ROWS_PER_BLOCK = 32;   // 4 waves x 8 rows
constexpr int THREADS = 256;
constexpr int CLEN = 256;            // c row length (M+1)
constexpr int NOUT = 512;            // IR length
constexpr int RHALVES = 280;         // 256-half ring + 24-half mirror (560B)

typedef float f4 __attribute__((ext_vector_type(4)));
typedef _Float16 half2_t __attribute__((ext_vector_type(2)));

// Sum v across each aligned 8-lane group; every lane gets the group total.
// Three DPP-fused adds: xor1, xor2 (quad_perm), xor4 (row_half_mirror).
__device__ __forceinline__ float row8_sum(float v) {
  asm("v_add_f32 %0, %0, %0 quad_perm:[1,0,3,2] row_mask:0xf bank_mask:0xf"
      : "+v"(v));
  asm("v_add_f32 %0, %0, %0 quad_perm:[2,3,0,1] row_mask:0xf bank_mask:0xf"
      : "+v"(v));
  asm("v_add_f32 %0, %0, %0 row_half_mirror row_mask:0xf bank_mask:0xf"
      : "+v"(v));
  return v;
}

// One window pair (2 f16 in wu) against 8 outputs; output j uses P[ub+7-j].
#define DOTQ(P, wu, ub)                                                \
      { const half2_t q = __builtin_bit_cast(half2_t, (wu));           \
        A0 = __builtin_amdgcn_fdot2(q, P[(ub) + 7], A0, false);        \
        A1 = __builtin_amdgcn_fdot2(q, P[(ub) + 6], A1, false);        \
        A2 = __builtin_amdgcn_fdot2(q, P[(ub) + 5], A2, false);        \
        A3 = __builtin_amdgcn_fdot2(q, P[(ub) + 4], A3, false);        \
        A4 = __builtin_amdgcn_fdot2(q, P[(ub) + 3], A4, false);        \
        A5 = __builtin_amdgcn_fdot2(q, P[(ub) + 2], A5, false);        \
        A6 = __builtin_amdgcn_fdot2(q, P[(ub) + 1], A6, false);        \
        A7 = __builtin_amdgcn_fdot2(q, P[(ub) + 0], A7, false); }

// Reduce + fixup + ring write (+mirror) + staging/flush.
// ITMOD: it&7 (literal in phase 2); DOFLUSH: literal bool.
#define ITER_TAIL(Y0EXPR, ITMOD, DOFLUSH)                                \
      const float a0 = row8_sum(A0);                                     \
      const float a1 = row8_sum(A1);                                     \
      const float a2 = row8_sum(A2);                                     \
      const float a3 = row8_sum(A3);                                     \
      const float a4 = row8_sum(A4);                                     \
      const float a5 = row8_sum(A5);                                     \
      const float a6 = row8_sum(A6);                                     \
      const float a7 = row8_sum(A7);                                     \
      const int n = it * 8;                                              \
      const f4 ivA = *(const f4*)(&INV[n]);                              \
      const f4 ivB = *(const f4*)(&INV[n + 4]);                          \
      const float y0 = (Y0EXPR);                                         \
      const float y1 = fmaf(kc1, y0, a1) * ivA.y;                        \
      const float y2 = fmaf(kc1, y1, fmaf(kc2, y0, a2)) * ivA.z;         \
      const float y3 = fmaf(kc1, y2, fmaf(kc2, y1,                       \
                          fmaf(kc3, y0, a3))) * ivA.w;                   \
      const float y4 = fmaf(kc1, y3, fmaf(kc2, y2, fmaf(kc3, y1,         \
                          fmaf(kc4, y0, a4)))) * ivB.x;                  \
      const float y5 = fmaf(kc1, y4, fmaf(kc2, y3, fmaf(kc3, y2,         \
                          fmaf(kc4, y1, fmaf(kc5, y0, a5))))) * ivB.y;   \
      const float y6 = fmaf(kc1, y5, fmaf(kc2, y4, fmaf(kc3, y3,         \
                          fmaf(kc4, y2, fmaf(kc5, y1,                    \
                          fmaf(kc6, y0, a6)))))) * ivB.z;                \
      const float y7 = fmaf(kc1, y6, fmaf(kc2, y5, fmaf(kc3, y4,         \
                          fmaf(kc4, y3, fmaf(kc5, y2, fmaf(kc6, y1,      \
                          fmaf(kc7, y0, a7)))))))  * ivB.w;              \
      uint4 wq;                                                          \
      wq.x = __builtin_bit_cast(uint, __builtin_amdgcn_cvt_pkrtz(y0, y1)); \
      wq.y = __builtin_bit_cast(uint, __builtin_amdgcn_cvt_pkrtz(y2, y3)); \
      wq.z = __builtin_bit_cast(uint, __builtin_amdgcn_cvt_pkrtz(y4, y5)); \
      wq.w = __builtin_bit_cast(uint, __builtin_amdgcn_cvt_pkrtz(y6, y7)); \
      qn = wq;                                                           \
      wo = (wo + 16) & 508;                                              \
      if (s == 0) {                                                      \
        *(uint4*)(Hb + wo) = wq;   /* same-wave DS ops are in-order */   \
        if (wo < 48) *(uint4*)(Hb + wo + 512) = wq;  /* mirror upkeep */ \
      }                                                                  \
      if ((ITMOD) == s) {                                                \
        ys0 = y0; ys1 = y1; ys2 = y2; ys3 = y3;                          \
        ys4 = y4; ys5 = y5; ys6 = y6; ys7 = y7;                          \
      }                                                                  \
      if (DOFLUSH) {                                                     \
        f4 v0; v0.x = ys0; v0.y = ys1; v0.z = ys2; v0.w = ys3;           \
        f4 v1; v1.x = ys4; v1.y = ys5; v1.z = ys6; v1.w = ys7;           \
        *(f4*)(gp) = v0;                                                 \
        *(f4*)(gp + 4) = v1;                                             \
        gp += 64;                                                        \
      }

// Phase-2 body: current window W0..W3, prefetch destination N0..N3
// (ping-pong). U = it&7 literal. Chunk reads: ro + {0,16,32,48} (mirror
// makes the immediates wrap-safe).
#define P2_BODY(U, W0, W1, W2, W3, N0, N1, N2, N3)                       \
    { const int it = itb + (U);                                          \
      N0 = *(const uint4*)(Hb + ro);                                     \
      N1 = *(const uint4*)(Hb + ro + 16);                                \
      N2 = *(const uint4*)(Hb + ro + 32);                                \
      N3 = *(const uint4*)(Hb + ro + 48);                                \
      ro = (ro + 16) & 508;                                              \
      uint4 w3u;                                                         \
      w3u.x = is7 ? qn.x : W3.x;                                         \
      w3u.y = is7 ? qn.y : W3.y;                                         \
      w3u.z = is7 ? qn.z : W3.z;                                         \
      w3u.w = is7 ? qn.w : W3.w;                                         \
      float A0 = 0.f, A1 = 0.f, A2 = 0.f, A3 = 0.f;                      \
      float A4 = 0.f, A5 = 0.f, A6 = 0.f, A7 = 0.f;                      \
      DOTQ(P, W0.x, 0)   DOTQ(P, W0.y, 2)                                \
      DOTQ(P, W0.z, 4)   DOTQ(P, W0.w, 6)                                \
      DOTQ(P, W1.x, 8)   DOTQ(P, W1.y, 10)                               \
      DOTQ(P, W1.z, 12)  DOTQ(P, W1.w, 14)                               \
      DOTQ(P, W2.x, 16)  DOTQ(P, W2.y, 18)                               \
      DOTQ(P, W2.z, 20)  DOTQ(P, W2.w, 22)                               \
      DOTQ(P, w3u.x, 24) DOTQ(P, w3u.y, 26)                              \
      DOTQ(P, w3u.z, 28) DOTQ(P, w3u.w, 30)                              \
      ITER_TAIL(a0 * ivA.x, (U), ((U) == 7))                             \
    }

__global__ __launch_bounds__(THREADS, 4) void cep2ir_kernel(
    const float* __restrict__ c, float* __restrict__ out, int nrows) {
  __shared__ ushort HF[ROWS_PER_BLOCK][RHALVES];   // f16 rings + mirror
  __shared__ float INV[NOUT];

  const int tid = threadIdx.x;
  const int lane = tid & 63;
  const int wid = tid >> 6;
  const int s = lane & 7;                  // sublane within 8-lane row group
  const int rl = (wid << 3) | (lane >> 3); // row within block, 0..31

  for (int i = tid; i < NOUT; i += THREADS)
    INV[i] = (i == 0) ? 0.0f : 1.0f / (float)i;
  // Zero all rings + mirrors (as uints; RHALVES even -> uint-aligned rows).
  uint* hz = (uint*)&HF[0][0];
  for (int i = tid; i < ROWS_PER_BLOCK * RHALVES / 2; i += THREADS)
    hz[i] = 0u;
  __syncthreads();  // uniform: all threads reach this before any divergence

  const long long row = (long long)blockIdx.x * ROWS_PER_BLOCK + rl;
  if (row < nrows) {
    const float* __restrict__ crow = c + row * (long long)CLEN;

    const float kc1 = crow[1];
    const float kc2 = 2.0f * crow[2];
    const float kc3 = 3.0f * crow[3];
    const float kc4 = 4.0f * crow[4];
    const float kc5 = 5.0f * crow[5];
    const float kc6 = 6.0f * crow[6];
    const float kc7 = 7.0f * crow[7];
    const float h0val = expf(crow[0]);
    const bool is7 = (s == 7);

    char* __restrict__ Hb = (char*)&HF[rl][0];
    int wo = (-16) & 508;                    // ring write offset (bytes)
    float* __restrict__ gp = out + row * (long long)NOUT + 8 * s;

    uint4 qn; qn.x = 0u; qn.y = 0u; qn.z = 0u; qn.w = 0u;  // forwarded h's

    // Register output staging: lane s keeps the y's of the iteration with
    // (it&7)==s, then writes its own 32B slice at flush (coalesced).
    float ys0 = 0.f, ys1 = 0.f, ys2 = 0.f, ys3 = 0.f;
    float ys4 = 0.f, ys5 = 0.f, ys6 = 0.f, ys7 = 0.f;

    // ------------- Phase 0: it = 0..7, 64-wide window -------------
    // Lane s owns pos p = 8s + e, e = 0..7. Coef k = K0 + j - e,
    // K0 = 64 - 8s; P0[u] = (kc(K0+7-u), kc(K0+6-u)), u = 0..13; pair pp
    // uses P0[2pp+7-j]. k in [2,71] -> no guards. Ring byte of p:
    // (16it + 384 + 16s) mod 512; newest 8 h's = lane 7's whole chunk.
    {
      const int K0 = 64 - 8 * s;
      half2_t P0[14];
#pragma unroll
      for (int u = 0; u < 14; ++u) {
        const int kx = K0 + 7 - u;          // in [2,71]; ky = kx-1 >= 1
        P0[u] = __builtin_bit_cast(half2_t, __builtin_amdgcn_cvt_pkrtz(
                    (float)kx * crow[kx], (float)(kx - 1) * crow[kx - 1]));
      }
#pragma unroll 2
      for (int it = 0; it < 8; ++it) {
        const int b = (16 * it + 384 + 16 * s) & 508;
        const uint4 r0 = *(const uint4*)(Hb + b);
        uint4 u0;
        u0.x = is7 ? qn.x : r0.x;
        u0.y = is7 ? qn.y : r0.y;
        u0.z = is7 ? qn.z : r0.z;
        u0.w = is7 ? qn.w : r0.w;

        float A0 = 0.f, A1 = 0.f, A2 = 0.f, A3 = 0.f;
        float A4 = 0.f, A5 = 0.f, A6 = 0.f, A7 = 0.f;
        DOTQ(P0, u0.x, 0) DOTQ(P0, u0.y, 2)
        DOTQ(P0, u0.z, 4) DOTQ(P0, u0.w, 6)

        ITER_TAIL((it == 0) ? h0val : a0 * ivA.x, (it & 7), ((it & 7) == 7))
      }
    }

    // ------------- Phase 1: it = 8..15, 128-wide window -------------
    // Lane s owns pos p = 16s + eps, eps = 0..15. K1 = 128 - 16s;
    // P1[u] = (kc(K1+7-u), kc(K1+6-u)), u = 0..21. k in [2,135] -> no
    // guards. Ring base (16it + 256 + 32s) mod 512; b1 = b0+16 is
    // wrap-safe via the mirror. Newest 8 = lane 7's upper chunk.
    {
      const int K1 = 128 - 16 * s;
      half2_t P1[22];
#pragma unroll
      for (int u = 0; u < 22; ++u) {
        const int kx = K1 + 7 - u;          // in [2,135]
        P1[u] = __builtin_bit_cast(half2_t, __builtin_amdgcn_cvt_pkrtz(
                    (float)kx * crow[kx], (float)(kx - 1) * crow[kx - 1]));
      }
#pragma unroll 2
      for (int it = 8; it < 16; ++it) {
        const int b0 = (16 * it + 256 + 32 * s) & 508;
        const uint4 u0 = *(const uint4*)(Hb + b0);        // eps 0..7
        const uint4 u1r = *(const uint4*)(Hb + b0 + 16);  // eps 8..15
        uint4 u1;
        u1.x = is7 ? qn.x : u1r.x;
        u1.y = is7 ? qn.y : u1r.y;
        u1.z = is7 ? qn.z : u1r.z;
        u1.w = is7 ? qn.w : u1r.w;

        float A0 = 0.f, A1 = 0.f, A2 = 0.f, A3 = 0.f;
        float A4 = 0.f, A5 = 0.f, A6 = 0.f, A7 = 0.f;
        DOTQ(P1, u0.x, 0)  DOTQ(P1, u0.y, 2)
        DOTQ(P1, u0.z, 4)  DOTQ(P1, u0.w, 6)
        DOTQ(P1, u1.x, 8)  DOTQ(P1, u1.y, 10)
        DOTQ(P1, u1.z, 12) DOTQ(P1, u1.w, 14)

        ITER_TAIL(a0 * ivA.x, (it & 7), ((it & 7) == 7))
      }
    }

    // ------------- Phase 2: it = 16..63, 256-wide window -------------
    // Lane s owns pos = 32s + eps, eps = 0..31. K = 256 - 32s.
    // P[u] = (kc(K+7-u), kc(K+6-u)), u = 0..37 (clamped outside [1,255]).
    // 8x unrolled (6 blocks), ping-pong windows, single rolling offset +
    // ds_read offset immediates (mirror makes them wrap-safe).
    {
      const int K = 256 - 32 * s;
      half2_t P[38];
#pragma unroll
      for (int u = 0; u < 38; ++u) {
        const int kx = K + 7 - u;
        const int ky = kx - 1;
        const float px = (kx >= 1 && kx <= 255) ? (float)kx * crow[kx] : 0.0f;
        const float py = (ky >= 1 && ky <= 255) ? (float)ky * crow[ky] : 0.0f;
        P[u] = __builtin_bit_cast(half2_t, __builtin_amdgcn_cvt_pkrtz(px, py));
      }

      // Prime window chunks for it=16; ro then points at it=17's base.
      int ro = (64 * s + 256) & 508;
      uint4 cw0 = *(const uint4*)(Hb + ro);
      uint4 cw1 = *(const uint4*)(Hb + ro + 16);
      uint4 cw2 = *(const uint4*)(Hb + ro + 32);
      uint4 cw3 = *(const uint4*)(Hb + ro + 48);
      ro = (ro + 16) & 508;
      uint4 pw0, pw1, pw2, pw3;

      for (int blk = 0; blk < 6; ++blk) {
        const int itb = 16 + 8 * blk;
        P2_BODY(0, cw0, cw1, cw2, cw3, pw0, pw1, pw2, pw3)
        P2_BODY(1, pw0, pw1, pw2, pw3, cw0, cw1, cw2, cw3)
        P2_BODY(2, cw0, cw1, cw2, cw3, pw0, pw1, pw2, pw3)
        P2_BODY(3, pw0, pw1, pw2, pw3, cw0, cw1, cw2, cw3)
        P2_BODY(4, cw0, cw1, cw2, cw3, pw0, pw1, pw2, pw3)
        P2_BODY(5, pw0, pw1, pw2, pw3, cw0, cw1, cw2, cw3)
        P2_BODY(6, cw0, cw1, cw2, cw3, pw0, pw1, pw2, pw3)
        P2_BODY(7, pw0, pw1, pw2, pw3, cw0, cw1, cw2, cw3)
      }
    }
  }
}

extern "C" void kernel_launch(void* const* d_in, const int* in_sizes, int n_in,
                              void* d_out, int out_size, void* d_ws, size_t ws_size,
                              hipStream_t stream) {
  const float* c = (const float*)d_in[0];
  float* out = (float*)d_out;
  const int nrows = in_sizes[0] / CLEN;
  const int nblocks = (nrows + ROWS_PER_BLOCK - 1) / ROWS_PER_BLOCK;
  hipLaunchKernelGGL(cep2ir_kernel, dim3(nblocks), dim3(THREADS), 0, stream,
                     c, out, nrows);
}

// Round 17
// 376.693 us; speedup vs baseline: 1.2296x; 1.2296x over previous
//
#include <hip/hip_runtime.h>
#include <math.h>

// CepstrumToImpulseResponse: per row r (131072 rows):
//   h[0] = exp(c[0]);  h[n] = (1/n) * sum_{k=1}^{min(n,255)} (k*c_k) * h[n-k]
//
// R17 = R15 restored verbatim (best measured: 375.7us, VALUBusy 96-97%).
// R16's 8x unroll expanded ~48 tail copies (>100KB phase-2 code) and
// thrashed the 32KiB L1I: VALUBusy 96->74.6 at unchanged VGPR/LDS/conflicts.
// Unroll depth on this kernel is I-cache-bounded; 2x ping-pong is the max.
//
// Final structure: 8 rows/wave (8 lanes/row), J=8 outputs/iter, per-row
// 256-half f16 ring, three-phase window (64/128/256-wide for it<8/<16/>=16;
// exact-zero skips), v_dot2_f32_f16 MACs (1 MAC/lane/cyc = HW max, proven
// across pk_f32/fdot2/pk_fma_f16), DPP-fused butterfly reduce, f32 serial
// fixup k=1..7, lane-7 register forwarding of the newest 8 h's, 1-iter
// window prefetch + phase-2 ping-pong 2x unroll, register output staging,
// 256B/row coalesced flush. Launch bounds (256,4): (256,8) spilled twice.

constexpr int ROWS_PER_BLOCK = 32;   // 4 waves x 8 rows
constexpr int THREADS = 256;
constexpr int CLEN = 256;            // c row length (M+1)
constexpr int NOUT = 512;            // IR length
constexpr int RHALVES = 264;         // 256-half ring (512B) + 8 pad halves

typedef float f4 __attribute__((ext_vector_type(4)));
typedef _Float16 half2_t __attribute__((ext_vector_type(2)));

// Sum v across each aligned 8-lane group; every lane gets the group total.
// Three DPP-fused adds: xor1 (quad_perm [1,0,3,2]), xor2 (quad_perm
// [2,3,0,1]), xor4 (row_half_mirror). dst = DPP(src0) + src1, all same reg.
__device__ __forceinline__ float row8_sum(float v) {
  asm("v_add_f32 %0, %0, %0 quad_perm:[1,0,3,2] row_mask:0xf bank_mask:0xf"
      : "+v"(v));
  asm("v_add_f32 %0, %0, %0 quad_perm:[2,3,0,1] row_mask:0xf bank_mask:0xf"
      : "+v"(v));
  asm("v_add_f32 %0, %0, %0 row_half_mirror row_mask:0xf bank_mask:0xf"
      : "+v"(v));
  return v;
}

// One window pair (2 f16 in wu) against 8 outputs; output j uses P[ub+7-j].
#define DOTQ(P, wu, ub)                                                \
      { const half2_t q = __builtin_bit_cast(half2_t, (wu));           \
        A0 = __builtin_amdgcn_fdot2(q, P[(ub) + 7], A0, false);        \
        A1 = __builtin_amdgcn_fdot2(q, P[(ub) + 6], A1, false);        \
        A2 = __builtin_amdgcn_fdot2(q, P[(ub) + 5], A2, false);        \
        A3 = __builtin_amdgcn_fdot2(q, P[(ub) + 4], A3, false);        \
        A4 = __builtin_amdgcn_fdot2(q, P[(ub) + 3], A4, false);        \
        A5 = __builtin_amdgcn_fdot2(q, P[(ub) + 2], A5, false);        \
        A6 = __builtin_amdgcn_fdot2(q, P[(ub) + 1], A6, false);        \
        A7 = __builtin_amdgcn_fdot2(q, P[(ub) + 0], A7, false); }

// Reduce + fixup + ring write + staging/flush (shared by all phases).
#define ITER_TAIL(Y0EXPR)                                                \
      const float a0 = row8_sum(A0);                                     \
      const float a1 = row8_sum(A1);                                     \
      const float a2 = row8_sum(A2);                                     \
      const float a3 = row8_sum(A3);                                     \
      const float a4 = row8_sum(A4);                                     \
      const float a5 = row8_sum(A5);                                     \
      const float a6 = row8_sum(A6);                                     \
      const float a7 = row8_sum(A7);                                     \
      const int n = it * 8;                                              \
      const f4 ivA = *(const f4*)(&INV[n]);                              \
      const f4 ivB = *(const f4*)(&INV[n + 4]);                          \
      const float y0 = (Y0EXPR);                                         \
      const float y1 = fmaf(kc1, y0, a1) * ivA.y;                        \
      const float y2 = fmaf(kc1, y1, fmaf(kc2, y0, a2)) * ivA.z;         \
      const float y3 = fmaf(kc1, y2, fmaf(kc2, y1,                       \
                          fmaf(kc3, y0, a3))) * ivA.w;                   \
      const float y4 = fmaf(kc1, y3, fmaf(kc2, y2, fmaf(kc3, y1,         \
                          fmaf(kc4, y0, a4)))) * ivB.x;                  \
      const float y5 = fmaf(kc1, y4, fmaf(kc2, y3, fmaf(kc3, y2,         \
                          fmaf(kc4, y1, fmaf(kc5, y0, a5))))) * ivB.y;   \
      const float y6 = fmaf(kc1, y5, fmaf(kc2, y4, fmaf(kc3, y3,         \
                          fmaf(kc4, y2, fmaf(kc5, y1,                    \
                          fmaf(kc6, y0, a6)))))) * ivB.z;                \
      const float y7 = fmaf(kc1, y6, fmaf(kc2, y5, fmaf(kc3, y4,         \
                          fmaf(kc4, y3, fmaf(kc5, y2, fmaf(kc6, y1,      \
                          fmaf(kc7, y0, a7)))))))  * ivB.w;              \
      uint4 wq;                                                          \
      wq.x = __builtin_bit_cast(uint, __builtin_amdgcn_cvt_pkrtz(y0, y1)); \
      wq.y = __builtin_bit_cast(uint, __builtin_amdgcn_cvt_pkrtz(y2, y3)); \
      wq.z = __builtin_bit_cast(uint, __builtin_amdgcn_cvt_pkrtz(y4, y5)); \
      wq.w = __builtin_bit_cast(uint, __builtin_amdgcn_cvt_pkrtz(y6, y7)); \
      qn = wq;                                                           \
      wo = (wo + 16) & 508;                                              \
      if (s == 0) {                                                      \
        *(uint4*)(Hb + wo) = wq;   /* same-wave DS ops are in-order */   \
      }                                                                  \
      if ((it & 7) == s) {                                               \
        ys0 = y0; ys1 = y1; ys2 = y2; ys3 = y3;                          \
        ys4 = y4; ys5 = y5; ys6 = y6; ys7 = y7;                          \
      }                                                                  \
      if ((it & 7) == 7) {                                               \
        f4 v0; v0.x = ys0; v0.y = ys1; v0.z = ys2; v0.w = ys3;           \
        f4 v1; v1.x = ys4; v1.y = ys5; v1.z = ys6; v1.w = ys7;           \
        *(f4*)(gp) = v0;                                                 \
        *(f4*)(gp + 4) = v1;                                             \
        gp += 64;                                                        \
      }

// Phase-2 iteration body: window regs W0..W3 (current), N0..N3 (prefetch
// destination for it+1). Roles ping-pong across the 2x-unrolled loop.
#define P2_BODY(W0, W1, W2, W3, N0, N1, N2, N3)                          \
    {                                                                    \
      N0 = *(const uint4*)(Hb + ro0);                                    \
      N1 = *(const uint4*)(Hb + ro1);                                    \
      N2 = *(const uint4*)(Hb + ro2);                                    \
      N3 = *(const uint4*)(Hb + ro3);                                    \
      ro0 = (ro0 + 16) & 508; ro1 = (ro1 + 16) & 508;                    \
      ro2 = (ro2 + 16) & 508; ro3 = (ro3 + 16) & 508;                    \
      uint4 w3u;                                                         \
      w3u.x = is7 ? qn.x : W3.x;                                         \
      w3u.y = is7 ? qn.y : W3.y;                                         \
      w3u.z = is7 ? qn.z : W3.z;                                         \
      w3u.w = is7 ? qn.w : W3.w;                                         \
      float A0 = 0.f, A1 = 0.f, A2 = 0.f, A3 = 0.f;                      \
      float A4 = 0.f, A5 = 0.f, A6 = 0.f, A7 = 0.f;                      \
      DOTQ(P, W0.x, 0)   DOTQ(P, W0.y, 2)                                \
      DOTQ(P, W0.z, 4)   DOTQ(P, W0.w, 6)                                \
      DOTQ(P, W1.x, 8)   DOTQ(P, W1.y, 10)                               \
      DOTQ(P, W1.z, 12)  DOTQ(P, W1.w, 14)                               \
      DOTQ(P, W2.x, 16)  DOTQ(P, W2.y, 18)                               \
      DOTQ(P, W2.z, 20)  DOTQ(P, W2.w, 22)                               \
      DOTQ(P, w3u.x, 24) DOTQ(P, w3u.y, 26)                              \
      DOTQ(P, w3u.z, 28) DOTQ(P, w3u.w, 30)                              \
      ITER_TAIL(a0 * ivA.x)                                              \
    }

__global__ __launch_bounds__(THREADS, 4) void cep2ir_kernel(
    const float* __restrict__ c, float* __restrict__ out, int nrows) {
  __shared__ ushort HF[ROWS_PER_BLOCK][RHALVES];   // f16 h-history rings
  __shared__ float INV[NOUT];

  const int tid = threadIdx.x;
  const int lane = tid & 63;
  const int wid = tid >> 6;
  const int s = lane & 7;                  // sublane within 8-lane row group
  const int rl = (wid << 3) | (lane >> 3); // row within block, 0..31

  for (int i = tid; i < NOUT; i += THREADS)
    INV[i] = (i == 0) ? 0.0f : 1.0f / (float)i;
  // Zero all rings (as uints; RHALVES is even -> rows stay uint-aligned).
  uint* hz = (uint*)&HF[0][0];
  for (int i = tid; i < ROWS_PER_BLOCK * RHALVES / 2; i += THREADS)
    hz[i] = 0u;
  __syncthreads();  // uniform: all threads reach this before any divergence

  const long long row = (long long)blockIdx.x * ROWS_PER_BLOCK + rl;
  if (row < nrows) {
    const float* __restrict__ crow = c + row * (long long)CLEN;

    const float kc1 = crow[1];
    const float kc2 = 2.0f * crow[2];
    const float kc3 = 3.0f * crow[3];
    const float kc4 = 4.0f * crow[4];
    const float kc5 = 5.0f * crow[5];
    const float kc6 = 6.0f * crow[6];
    const float kc7 = 7.0f * crow[7];
    const float h0val = expf(crow[0]);
    const bool is7 = (s == 7);

    char* __restrict__ Hb = (char*)&HF[rl][0];
    int wo = (-16) & 508;                    // ring write offset (bytes)
    float* __restrict__ gp = out + row * (long long)NOUT + 8 * s;

    uint4 qn; qn.x = 0u; qn.y = 0u; qn.z = 0u; qn.w = 0u;  // forwarded h's

    // Register output staging: lane s keeps the y's of the iteration with
    // (it&7)==s, then writes its own 32B slice at flush (coalesced).
    float ys0 = 0.f, ys1 = 0.f, ys2 = 0.f, ys3 = 0.f;
    float ys4 = 0.f, ys5 = 0.f, ys6 = 0.f, ys7 = 0.f;

    // ------------- Phase 0: it = 0..7, 64-wide window -------------
    // Lane s owns pos p = 8s + e, e = 0..7 (p 0 = h[n-64], p 63 = h[n-1]).
    // Coef k = K0 + j - e, K0 = 64 - 8s; P0[u] = (kc(K0+7-u), kc(K0+6-u)),
    // u = 0..13; pair pp (e = 2pp,2pp+1) for output j uses P0[2pp+7-j].
    // k over all lanes in [2,71] -> no guards. Ring byte of p:
    // (16it + 384 + 16s + 2e) mod 512; newest 8 h's = lane 7's whole chunk.
    {
      const int K0 = 64 - 8 * s;
      half2_t P0[14];
#pragma unroll
      for (int u = 0; u < 14; ++u) {
        const int kx = K0 + 7 - u;          // in [2,71]; ky = kx-1 >= 1
        P0[u] = __builtin_bit_cast(half2_t, __builtin_amdgcn_cvt_pkrtz(
                    (float)kx * crow[kx], (float)(kx - 1) * crow[kx - 1]));
      }
#pragma unroll 2
      for (int it = 0; it < 8; ++it) {
        const int b = (16 * it + 384 + 16 * s) & 508;
        const uint4 r0 = *(const uint4*)(Hb + b);
        uint4 u0;
        u0.x = is7 ? qn.x : r0.x;
        u0.y = is7 ? qn.y : r0.y;
        u0.z = is7 ? qn.z : r0.z;
        u0.w = is7 ? qn.w : r0.w;

        float A0 = 0.f, A1 = 0.f, A2 = 0.f, A3 = 0.f;
        float A4 = 0.f, A5 = 0.f, A6 = 0.f, A7 = 0.f;
        DOTQ(P0, u0.x, 0) DOTQ(P0, u0.y, 2)
        DOTQ(P0, u0.z, 4) DOTQ(P0, u0.w, 6)

        ITER_TAIL((it == 0) ? h0val : a0 * ivA.x)
      }
    }

    // ------------- Phase 1: it = 8..15, 128-wide window -------------
    // Lane s owns pos p = 16s + eps, eps = 0..15. K1 = 128 - 16s;
    // P1[u] = (kc(K1+7-u), kc(K1+6-u)), u = 0..21; pair pp uses P1[2pp+7-j].
    // k over all lanes in [2,135] -> no guards. Ring byte of p:
    // (16it + 256 + 32s + 2eps) mod 512. Newest 8 = lane 7's upper chunk.
    {
      const int K1 = 128 - 16 * s;
      half2_t P1[22];
#pragma unroll
      for (int u = 0; u < 22; ++u) {
        const int kx = K1 + 7 - u;          // in [2,135]
        P1[u] = __builtin_bit_cast(half2_t, __builtin_amdgcn_cvt_pkrtz(
                    (float)kx * crow[kx], (float)(kx - 1) * crow[kx - 1]));
      }
#pragma unroll 2
      for (int it = 8; it < 16; ++it) {
        const int b0 = (16 * it + 256 + 32 * s) & 508;
        const int b1 = (b0 + 16) & 508;
        const uint4 u0 = *(const uint4*)(Hb + b0);   // eps 0..7
        const uint4 u1r = *(const uint4*)(Hb + b1);  // eps 8..15
        uint4 u1;
        u1.x = is7 ? qn.x : u1r.x;
        u1.y = is7 ? qn.y : u1r.y;
        u1.z = is7 ? qn.z : u1r.z;
        u1.w = is7 ? qn.w : u1r.w;

        float A0 = 0.f, A1 = 0.f, A2 = 0.f, A3 = 0.f;
        float A4 = 0.f, A5 = 0.f, A6 = 0.f, A7 = 0.f;
        DOTQ(P1, u0.x, 0)  DOTQ(P1, u0.y, 2)
        DOTQ(P1, u0.z, 4)  DOTQ(P1, u0.w, 6)
        DOTQ(P1, u1.x, 8)  DOTQ(P1, u1.y, 10)
        DOTQ(P1, u1.z, 12) DOTQ(P1, u1.w, 14)

        ITER_TAIL(a0 * ivA.x)
      }
    }

    // ------------- Phase 2: it = 16..63, 256-wide window -------------
    // Lane s owns pos = 32s + eps, eps = 0..31. K = 256 - 32s.
    // P[u] = (kc(K+7-u), kc(K+6-u)), u = 0..37 (clamped outside [1,255]).
    // 2x-unrolled with ping-pong window registers (no rotation moves).
    {
      const int K = 256 - 32 * s;
      half2_t P[38];
#pragma unroll
      for (int u = 0; u < 38; ++u) {
        const int kx = K + 7 - u;
        const int ky = kx - 1;
        const float px = (kx >= 1 && kx <= 255) ? (float)kx * crow[kx] : 0.0f;
        const float py = (ky >= 1 && ky <= 255) ? (float)ky * crow[ky] : 0.0f;
        P[u] = __builtin_bit_cast(half2_t, __builtin_amdgcn_cvt_pkrtz(px, py));
      }

      // Prime window chunks for it=16; rolling offsets point at it=17.
      // Chunk cix byte offset at iter it: (64s + 16cix + 16it) & 508.
      uint4 cw0 = *(const uint4*)(Hb + ((64 * s + 0  + 256) & 508));
      uint4 cw1 = *(const uint4*)(Hb + ((64 * s + 16 + 256) & 508));
      uint4 cw2 = *(const uint4*)(Hb + ((64 * s + 32 + 256) & 508));
      uint4 cw3 = *(const uint4*)(Hb + ((64 * s + 48 + 256) & 508));
      int ro0 = (64 * s + 0  + 272) & 508;
      int ro1 = (64 * s + 16 + 272) & 508;
      int ro2 = (64 * s + 32 + 272) & 508;
      int ro3 = (64 * s + 48 + 272) & 508;
      uint4 pw0, pw1, pw2, pw3;

      for (int itp = 16; itp < 64; itp += 2) {
        { const int it = itp;
          P2_BODY(cw0, cw1, cw2, cw3, pw0, pw1, pw2, pw3) }
        { const int it = itp + 1;
          P2_BODY(pw0, pw1, pw2, pw3, cw0, cw1, cw2, cw3) }
      }
    }
  }
}

extern "C" void kernel_launch(void* const* d_in, const int* in_sizes, int n_in,
                              void* d_out, int out_size, void* d_ws, size_t ws_size,
                              hipStream_t stream) {
  const float* c = (const float*)d_in[0];
  float* out = (float*)d_out;
  const int nrows = in_sizes[0] / CLEN;
  const int nblocks = (nrows + ROWS_PER_BLOCK - 1) / ROWS_PER_BLOCK;
  hipLaunchKernelGGL(cep2ir_kernel, dim3(nblocks), dim3(THREADS), 0, stream,
                     c, out, nrows);
}